// Round 8
// baseline (369.442 us; speedup 1.0000x reference)
//
#include <hip/hip_runtime.h>
#include <cstddef>

#define NEDGES   800000
#define NRAD     32
#define MAXZ     100
#define NGRP     (NEDGES / 16)                   // 50000 groups of 16 edges
#define T1_OFF   0
#define T2_OFF   (MAXZ * 128)                    // 12800 floats
#define WC_OFF   (2 * MAXZ * 128)                // 25600 floats
#define FB_OFF   (2 * MAXZ * 128 + NRAD * 128)   // 29696 floats (B-frags, 8KB)
#define ZP_OFF   (FB_OFF + 2048)                 // then 800000 ints

typedef __attribute__((ext_vector_type(8))) short bf16x8;
typedef __attribute__((ext_vector_type(4))) float f32x4;

__device__ inline unsigned short f2bf(float f) {            // RTNE f32->bf16
    unsigned u = __float_as_uint(f);
    u += 0x7FFFu + ((u >> 16) & 1u);
    return (unsigned short)(u >> 16);
}
__device__ inline float silu(float v) {
    return v * __builtin_amdgcn_rcpf(1.f + __expf(-v));
}

// ---------------------------------------------------------------------------
// Prep A: fold weights into tables.
// ---------------------------------------------------------------------------
__global__ __launch_bounds__(128)
void prep_kernel(const float* __restrict__ embed_w,
                 const float* __restrict__ w_rbf,
                 const float* __restrict__ w_edge,
                 const float* __restrict__ b_edge,
                 float* __restrict__ ws) {
    const int d = threadIdx.x;
    const int b = blockIdx.x;
    if (b < MAXZ) {
        float a1 = b_edge[d];
        float a2 = 0.f;
        #pragma unroll 8
        for (int k = 0; k < 128; ++k) {
            const float e = embed_w[b * 128 + k];
            a1 = fmaf(e, w_edge[k * 128 + d], a1);
            a2 = fmaf(e, w_edge[(128 + k) * 128 + d], a2);
        }
        ws[T1_OFF + b * 128 + d] = a1;
        ws[T2_OFF + b * 128 + d] = a2;
    } else {
        const int q = b - MAXZ;
        float a = 0.f;
        #pragma unroll 8
        for (int m = 0; m < 128; ++m)
            a = fmaf(w_rbf[q * 128 + m], w_edge[(256 + m) * 128 + d], a);
        ws[WC_OFF + q * 128 + d] = a;
    }
}

// ---------------------------------------------------------------------------
// Prep B: B-fragments of Wc in MFMA lane order.
// ---------------------------------------------------------------------------
__global__ __launch_bounds__(512)
void prep_b_kernel(const float* __restrict__ ws_in, float* __restrict__ ws) {
    const int tid  = threadIdx.x;
    const int g    = tid >> 6;
    const int lane = tid & 63;
    const int n16  = lane & 15;
    const int kh   = lane >> 4;
    unsigned short* FB = (unsigned short*)(ws + FB_OFF);
    #pragma unroll
    for (int j = 0; j < 8; ++j)
        FB[(g * 64 + lane) * 8 + j] =
            f2bf(ws_in[WC_OFF + (kh * 8 + j) * 128 + 16 * g + n16]);
}

__global__ __launch_bounds__(256)
void zp_kernel(const int* __restrict__ x,
               const int* __restrict__ idx_i,
               const int* __restrict__ idx_j,
               int* __restrict__ zp) {
    const int e = blockIdx.x * 256 + threadIdx.x;
    zp[e] = (x[idx_j[e]] << 8) | x[idx_i[e]];
}

// ---------------------------------------------------------------------------
// PROBE: R5 per-wave structure, but each wave runs TWO independent groups
// (w and (w+25000)%50000) -> every group computed twice (byte-identical
// duplicate stores, benign). Purpose:
//   (a) dispatch is ~2x long -> edge counters become visible in top-5
//   (b) 2 independent chains/wave test the latency/MLP hypothesis
// A-tiles + zp of both chains loaded up front so HBM latencies overlap.
// ---------------------------------------------------------------------------
__global__ __launch_bounds__(256, 4)
void edge_kernel2(const float* __restrict__ rbf,
                  const int* __restrict__ zp,
                  const float* __restrict__ ws,
                  float* __restrict__ out) {
    const int lane = threadIdx.x & 63;
    const int wid  = threadIdx.x >> 6;
    const int n16  = lane & 15;
    const int kh   = lane >> 4;
    const int w    = blockIdx.x * 4 + wid;          // 0..49999

    int g2 = w + NGRP / 2;
    if (g2 >= NGRP) g2 -= NGRP;
    const int eb[2] = {__builtin_amdgcn_readfirstlane(w * 16),
                       __builtin_amdgcn_readfirstlane(g2 * 16)};

    const float* __restrict__ T1 = ws + T1_OFF;
    const float* __restrict__ T2 = ws + T2_OFF;
    const bf16x8* __restrict__ FB = (const bf16x8*)(ws + FB_OFF);

    // ---- load phase: both chains' HBM loads in flight together ----
    f32x4 A0[2], A4[2];
    int4  ZPV[2];
    #pragma unroll
    for (int c = 0; c < 2; ++c) {
        const f32x4* arow = (const f32x4*)(rbf + (size_t)(eb[c] + n16) * NRAD + kh * 8);
        A0[c] = __builtin_nontemporal_load(arow);
        A4[c] = __builtin_nontemporal_load(arow + 1);
        ZPV[c] = *(const int4*)(zp + eb[c] + kh * 4);
    }

    bf16x8 bhi[8];
    #pragma unroll
    for (int g = 0; g < 8; ++g)
        bhi[g] = FB[g * 64 + lane];

    // ---- compute phase: chain 0 fully, then chain 1 ----
    #pragma unroll
    for (int c = 0; c < 2; ++c) {
        bf16x8 ahi;
        ahi[0] = (short)f2bf(A0[c].x); ahi[1] = (short)f2bf(A0[c].y);
        ahi[2] = (short)f2bf(A0[c].z); ahi[3] = (short)f2bf(A0[c].w);
        ahi[4] = (short)f2bf(A4[c].x); ahi[5] = (short)f2bf(A4[c].y);
        ahi[6] = (short)f2bf(A4[c].z); ahi[7] = (short)f2bf(A4[c].w);

        f32x4 acc[8];
        #pragma unroll
        for (int g = 0; g < 8; ++g) {
            acc[g] = (f32x4){0.f, 0.f, 0.f, 0.f};
            acc[g] = __builtin_amdgcn_mfma_f32_16x16x32_bf16(ahi, bhi[g], acc[g], 0, 0, 0);
        }

        const int zv[4] = {ZPV[c].x, ZPV[c].y, ZPV[c].z, ZPV[c].w};
        #pragma unroll
        for (int r = 0; r < 4; ++r) {
            const int zj = zv[r] >> 8;
            const int zi = zv[r] & 0xFF;
            const float* __restrict__ t1p = T1 + zj * 128 + n16;
            const float* __restrict__ t2p = T2 + zi * 128 + n16;
            float* __restrict__ op = out + (size_t)(eb[c] + kh * 4 + r) * 128 + n16;
            #pragma unroll
            for (int g = 0; g < 8; ++g) {
                const float v = acc[g][r] + t1p[16 * g] + t2p[16 * g];
                op[16 * g] = silu(v);
            }
        }
    }
}

extern "C" void kernel_launch(void* const* d_in, const int* in_sizes, int n_in,
                              void* d_out, int out_size, void* d_ws, size_t ws_size,
                              hipStream_t stream) {
    const int*   x       = (const int*)d_in[0];
    const float* rbf     = (const float*)d_in[1];
    const int*   idx_i   = (const int*)d_in[2];
    const int*   idx_j   = (const int*)d_in[3];
    const float* embed_w = (const float*)d_in[4];
    const float* w_rbf   = (const float*)d_in[5];
    const float* w_edge  = (const float*)d_in[6];
    const float* b_edge  = (const float*)d_in[7];
    float* out = (float*)d_out;
    float* ws  = (float*)d_ws;
    int*   zp  = (int*)(ws + ZP_OFF);

    prep_kernel<<<MAXZ + NRAD, 128, 0, stream>>>(embed_w, w_rbf, w_edge, b_edge, ws);
    prep_b_kernel<<<1, 512, 0, stream>>>(ws, ws);
    zp_kernel<<<NEDGES / 256, 256, 0, stream>>>(x, idx_i, idx_j, zp);
    edge_kernel2<<<NGRP / 4, 256, 0, stream>>>(rbf, zp, ws, out);
}

// Round 10
// 157.214 us; speedup vs baseline: 2.3499x; 2.3499x over previous
//
#include <hip/hip_runtime.h>
#include <cstddef>

#define NEDGES   800000
#define NRAD     32
#define MAXZ     100
#define NGRP     (NEDGES / 16)                   // 50000 groups of 16 edges
#define NBLK     768                             // persistent blocks (3/CU)
#define T1_OFF   0
#define T2_OFF   (MAXZ * 128)                    // 12800 floats
#define WC_OFF   (2 * MAXZ * 128)                // 25600 floats
#define FB_OFF   (WC_OFF + NRAD * 128)           // 29696 floats (B-frags, 8KB)
#define PT_OFF   (FB_OFF + 2048)                 // 31744 floats (packed bf16 tables, 51.2KB)
#define ZP_OFF   (PT_OFF + 12800)                // 44544 floats, then 800000 ints

typedef __attribute__((ext_vector_type(8))) short bf16x8;
typedef __attribute__((ext_vector_type(4))) float f32x4;
typedef __attribute__((ext_vector_type(4))) unsigned int u32x4;

__device__ inline unsigned short f2bf(float f) {            // RTNE f32->bf16
    unsigned u = __float_as_uint(f);
    u += 0x7FFFu + ((u >> 16) & 1u);
    return (unsigned short)(u >> 16);
}
__device__ inline float silu(float v) {
    return v * __builtin_amdgcn_rcpf(1.f + __expf(-v));
}

// ---------------------------------------------------------------------------
// Prep A: fold weights into tables (f32 master copies in ws).
// ---------------------------------------------------------------------------
__global__ __launch_bounds__(128)
void prep_kernel(const float* __restrict__ embed_w,
                 const float* __restrict__ w_rbf,
                 const float* __restrict__ w_edge,
                 const float* __restrict__ b_edge,
                 float* __restrict__ ws) {
    const int d = threadIdx.x;
    const int b = blockIdx.x;
    if (b < MAXZ) {
        float a1 = b_edge[d];
        float a2 = 0.f;
        #pragma unroll 8
        for (int k = 0; k < 128; ++k) {
            const float e = embed_w[b * 128 + k];
            a1 = fmaf(e, w_edge[k * 128 + d], a1);
            a2 = fmaf(e, w_edge[(128 + k) * 128 + d], a2);
        }
        ws[T1_OFF + b * 128 + d] = a1;
        ws[T2_OFF + b * 128 + d] = a2;
    } else {
        const int q = b - MAXZ;
        float a = 0.f;
        #pragma unroll 8
        for (int m = 0; m < 128; ++m)
            a = fmaf(w_rbf[q * 128 + m], w_edge[(256 + m) * 128 + d], a);
        ws[WC_OFF + q * 128 + d] = a;
    }
}

// ---------------------------------------------------------------------------
// Prep B: B-fragments of Wc in MFMA lane order (coalesced 16B loads later).
// ---------------------------------------------------------------------------
__global__ __launch_bounds__(512)
void prep_b_kernel(const float* __restrict__ ws_in, float* __restrict__ ws) {
    const int tid  = threadIdx.x;
    const int g    = tid >> 6;
    const int lane = tid & 63;
    const int n16  = lane & 15;
    const int kh   = lane >> 4;
    unsigned short* FB = (unsigned short*)(ws + FB_OFF);
    #pragma unroll
    for (int j = 0; j < 8; ++j)
        FB[(g * 64 + lane) * 8 + j] =
            f2bf(ws_in[WC_OFF + (kh * 8 + j) * 128 + 16 * g + n16]);
}

// ---------------------------------------------------------------------------
// Prep C: packed bf16 tables, lane-friendly layout:
//   PT[z][n16*8 + g] = bf16(T[z][16g + n16]),  z in [0,200) (T1 rows then T2)
// so a lane's 8 per-row entries are 16 CONTIGUOUS bytes (one ds_read_b128).
// ---------------------------------------------------------------------------
__global__ __launch_bounds__(128)
void prep_pack_kernel(const float* __restrict__ ws_in, float* __restrict__ ws) {
    const int z = blockIdx.x;            // 0..199
    const int d = threadIdx.x;           // 0..127 = n16*8 + g
    const int n16 = d >> 3, g = d & 7;
    const float v = (z < MAXZ)
        ? ws_in[T1_OFF + z * 128 + 16 * g + n16]
        : ws_in[T2_OFF + (z - MAXZ) * 128 + 16 * g + n16];
    ((unsigned short*)(ws + PT_OFF))[z * 128 + d] = f2bf(v);
}

__global__ __launch_bounds__(256)
void zp_kernel(const int* __restrict__ x,
               const int* __restrict__ idx_i,
               const int* __restrict__ idx_j,
               int* __restrict__ zp) {
    const int e = blockIdx.x * 256 + threadIdx.x;
    zp[e] = (x[idx_j[e]] << 8) | x[idx_i[e]];
}

// ---------------------------------------------------------------------------
// Main: persistent blocks. Stage packed bf16 T1/T2 into LDS once (51.2KB,
// 3 blocks/CU), then grid-stride over 16-edge groups with next-group
// A-tile/zp prefetch. Table gathers: 8 conflict-free ds_read_b128 per group
// (was 64 global loads = 256 L2 line-requests — the diagnosed binder).
// R9 bug: staging copy covered only 3200/6400 uint2 (T2 half of LDS was
// uninitialized -> NaN). Fixed: 6400.
// ---------------------------------------------------------------------------
__global__ __launch_bounds__(256, 3)
void edge_kernel(const float* __restrict__ rbf,
                 const int* __restrict__ zp,
                 const float* __restrict__ ws,
                 float* __restrict__ out) {
    __shared__ unsigned short sT[200 * 128];     // 51200 B

    const int tid = threadIdx.x;
    {   // stage packed tables (once per block): 51200 B = 6400 uint2
        const uint2* __restrict__ src = (const uint2*)(ws + PT_OFF);
        uint2* dst = (uint2*)sT;
        for (int i = tid; i < 6400; i += 256) dst[i] = src[i];
    }
    __syncthreads();

    const int lane = tid & 63;
    const int wid  = tid >> 6;
    const int n16  = lane & 15;
    const int kh   = lane >> 4;

    const bf16x8* __restrict__ FB = (const bf16x8*)(ws + FB_OFF);
    bf16x8 bhi[8];
    #pragma unroll
    for (int g = 0; g < 8; ++g) {
        bhi[g] = FB[g * 64 + lane];
        asm volatile("" : "+v"(bhi[g]));         // pin: no remat from memory
    }

    const int STRIDE = NBLK * 4;
    int grp = blockIdx.x * 4 + wid;

    // prime current group's loads
    f32x4 cA0 = {0.f,0.f,0.f,0.f}, cA4 = {0.f,0.f,0.f,0.f};
    int4  cZ  = {0,0,0,0};
    {
        const int eb = grp * 16;
        const f32x4* ar = (const f32x4*)(rbf + (size_t)(eb + n16) * NRAD + kh * 8);
        cA0 = ar[0]; cA4 = ar[1];
        cZ  = *(const int4*)(zp + eb + kh * 4);
    }

    while (grp < NGRP) {
        const int ng = grp + STRIDE;
        f32x4 nA0 = {0.f,0.f,0.f,0.f}, nA4 = {0.f,0.f,0.f,0.f};
        int4  nZ  = {0,0,0,0};
        if (ng < NGRP) {                          // prefetch next group
            const int eb2 = ng * 16;
            const f32x4* ar = (const f32x4*)(rbf + (size_t)(eb2 + n16) * NRAD + kh * 8);
            nA0 = ar[0]; nA4 = ar[1];
            nZ  = *(const int4*)(zp + eb2 + kh * 4);
        }

        const int ebase = grp * 16;

        bf16x8 ahi;
        ahi[0] = (short)f2bf(cA0.x); ahi[1] = (short)f2bf(cA0.y);
        ahi[2] = (short)f2bf(cA0.z); ahi[3] = (short)f2bf(cA0.w);
        ahi[4] = (short)f2bf(cA4.x); ahi[5] = (short)f2bf(cA4.y);
        ahi[6] = (short)f2bf(cA4.z); ahi[7] = (short)f2bf(cA4.w);

        f32x4 acc[8];
        #pragma unroll
        for (int g = 0; g < 8; ++g) {
            acc[g] = (f32x4){0.f, 0.f, 0.f, 0.f};
            acc[g] = __builtin_amdgcn_mfma_f32_16x16x32_bf16(ahi, bhi[g], acc[g], 0, 0, 0);
        }

        const int zv[4] = {cZ.x, cZ.y, cZ.z, cZ.w};
        #pragma unroll
        for (int r = 0; r < 4; ++r) {
            const int zj = zv[r] >> 8;
            const int zi = zv[r] & 0xFF;
            const u32x4 q1 = *(const u32x4*)(sT + zj * 128 + n16 * 8);
            const u32x4 q2 = *(const u32x4*)(sT + (MAXZ + zi) * 128 + n16 * 8);
            float* __restrict__ op = out + (size_t)(ebase + kh * 4 + r) * 128 + n16;
            #pragma unroll
            for (int k = 0; k < 4; ++k) {
                const float t1a = __uint_as_float(q1[k] << 16);
                const float t1b = __uint_as_float(q1[k] & 0xFFFF0000u);
                const float t2a = __uint_as_float(q2[k] << 16);
                const float t2b = __uint_as_float(q2[k] & 0xFFFF0000u);
                const float v0 = acc[2 * k][r]     + t1a + t2a;
                const float v1 = acc[2 * k + 1][r] + t1b + t2b;
                op[16 * (2 * k)]     = silu(v0);
                op[16 * (2 * k + 1)] = silu(v1);
            }
        }

        cA0 = nA0; cA4 = nA4; cZ = nZ;
        grp = ng;
    }
}

extern "C" void kernel_launch(void* const* d_in, const int* in_sizes, int n_in,
                              void* d_out, int out_size, void* d_ws, size_t ws_size,
                              hipStream_t stream) {
    const int*   x       = (const int*)d_in[0];
    const float* rbf     = (const float*)d_in[1];
    const int*   idx_i   = (const int*)d_in[2];
    const int*   idx_j   = (const int*)d_in[3];
    const float* embed_w = (const float*)d_in[4];
    const float* w_rbf   = (const float*)d_in[5];
    const float* w_edge  = (const float*)d_in[6];
    const float* b_edge  = (const float*)d_in[7];
    float* out = (float*)d_out;
    float* ws  = (float*)d_ws;
    int*   zp  = (int*)(ws + ZP_OFF);

    prep_kernel<<<MAXZ + NRAD, 128, 0, stream>>>(embed_w, w_rbf, w_edge, b_edge, ws);
    prep_b_kernel<<<1, 512, 0, stream>>>(ws, ws);
    prep_pack_kernel<<<2 * MAXZ, 128, 0, stream>>>(ws, ws);
    zp_kernel<<<NEDGES / 256, 256, 0, stream>>>(x, idx_i, idx_j, zp);
    edge_kernel<<<NBLK, 256, 0, stream>>>(rbf, zp, ws, out);
}